// Round 9
// baseline (139.155 us; speedup 1.0000x reference)
//
#include <hip/hip_runtime.h>

#define NN 2048
#define GG 64
#define TS 128
#define NT (NN / TS)                 // 16 tiles
#define NPAIR (NT * (NT + 1) / 2)    // 136 tile pairs
#define MAXE 14336                   // per-image edge cap (est. E ~ 3000)
#define STH 512                      // scan threads

typedef unsigned long long u64;
typedef unsigned short u16;
typedef unsigned int u32;

__device__ __forceinline__ float iou4(float4 a, float4 b) {
    float w = fminf(a.z, b.z) - fmaxf(a.x, b.x) + 1.0f;
    float h = fminf(a.w, b.w) - fmaxf(a.y, b.y) + 1.0f;
    w = fmaxf(w, 0.0f);
    h = fmaxf(h, 0.0f);
    float ov = w * h;
    float aa = (a.z - a.x + 1.0f) * (a.w - a.y + 1.0f);
    float ab = (b.z - b.x + 1.0f) * (b.w - b.y + 1.0f);
    return ov / (aa + ab - ov);
}

__device__ __forceinline__ float wredf(float v) {
    for (int o = 32; o > 0; o >>= 1) v += __shfl_down(v, o);
    return v;
}
__device__ __forceinline__ int wredi(int v) {
    for (int o = 32; o > 0; o >>= 1) v += __shfl_down(v, o);
    return v;
}

// selection order: earlier = higher score, tie -> lower original index.
// scores >= 0 so float bits compare as uint.
__device__ __forceinline__ bool earlier(u32 sa, int a, u32 sb, int b) {
    return (sa > sb) || (sa == sb && a < b);
}
__device__ __forceinline__ u64 make_key(u32 sbits, int j) {
    return ((u64)sbits << 32) | (u64)(NN - 1 - j);
}
__device__ __forceinline__ float4 load_box(const float* pb, int j) {
    return make_float4(pb[j * 5 + 0], pb[j * 5 + 1], pb[j * 5 + 2], pb[j * 5 + 3]);
}

// ---------------- K1: balanced LDS-tiled pair phase -> compact edge list ----------------
// grid: B*NPAIR blocks, 256 threads; block = (im, tile-pair a<=b) over original order.
__global__ __launch_bounds__(256) void pair_kernel(const int* __restrict__ gt_inds,
                                                   const float* __restrict__ props,
                                                   int* __restrict__ ecnt, u32* __restrict__ edges) {
    const int im = blockIdx.x / NPAIR;
    int q = blockIdx.x % NPAIR;
    int ta = 0;
    while (q >= NT - ta) { q -= NT - ta; ++ta; }
    const int tb = ta + q;
    const float* pb = props + (size_t)im * NN * 5;
    const int* gbi = gt_inds + (size_t)im * NN;

    __shared__ float4 Abox[TS], Bbox[TS];
    __shared__ u32 Asc[TS], Bsc[TS];
    __shared__ int Ag[TS], Bg[TS];
    const int tid = threadIdx.x;

    for (int t = tid; t < 2 * TS; t += 256) {
        int half = t >> 7, r = t & (TS - 1);
        int j = (half ? tb : ta) * TS + r;
        float4 bx = load_box(pb, j);
        u32 sb = __float_as_uint(pb[j * 5 + 4]);
        int g = gbi[j];
        if (half == 0) { Abox[r] = bx; Asc[r] = sb; Ag[r] = g; }
        else           { Bbox[r] = bx; Bsc[r] = sb; Bg[r] = g; }
    }
    __syncthreads();

    const int pr = tid & (TS - 1);      // row in tile A
    const int half = tid >> 7;          // column half in tile B
    const float4 rb = Abox[pr];
    const u32 rs = Asc[pr];
    const int i = ta * TS + pr;
    u32* ge = edges + (size_t)im * MAXE;
    if (Ag[pr] >= 0) {
        #pragma unroll 4
        for (int k = 0; k < TS / 2; ++k) {
            int jl = half * (TS / 2) + k;
            if (ta == tb && jl <= pr) continue;   // each unordered pair once
            if (Bg[jl] < 0) continue;
            float v = iou4(rb, Bbox[jl]);
            if (v > 0.5f) {
                int j = tb * TS + jl;
                int late, early;
                if (earlier(rs, i, Bsc[jl], j)) { late = j; early = i; }
                else                            { late = i; early = j; }
                int slot = atomicAdd(&ecnt[im], 1);
                if (slot < MAXE) ge[slot] = ((u32)late << 16) | (u32)early;
            }
        }
    }
}

// ---------------- K2: LDS CSR build + fixpoint + attribution + fused finalize ----------------
__global__ __launch_bounds__(STH) void scan_kernel(const int* __restrict__ gt_inds,
                                                   const float* __restrict__ gt_boxes,
                                                   const float* __restrict__ props,
                                                   const int* __restrict__ ecnt, const u32* __restrict__ edges,
                                                   float* __restrict__ acc, u32* __restrict__ ctr2,
                                                   float* __restrict__ out, int B) {
    __shared__ u32 scoreL[NN];            // 8 KB (float bits)
    __shared__ float sumA[NN];            // 8 KB
    __shared__ int cw[NN];                // 8 KB: count -> cursor -> cntA (re-zeroed)
    __shared__ u16 eoff[NN + 1];          // 4 KB
    __shared__ u16 ent[MAXE];             // 28 KB
    __shared__ unsigned char st[NN];      // 0=unresolved 1=kept 2=killed
    __shared__ unsigned char hk[NN];
    __shared__ float4 gtb[GG];            // 1 KB
    __shared__ u64 firstk[GG];            // max key among kept per gt (0 = none)
    __shared__ int wtot[STH / 64];
    __shared__ u64 s_minkey;
    __shared__ int s_unres, s_pos, s_qcnt, s_pcnt;
    __shared__ float s_tpush, s_tpull;

    const int im = blockIdx.x, tid = threadIdx.x;
    const int lane = tid & 63, wid = tid >> 6;
    const float* pb = props + (size_t)im * NN * 5;
    const int* gbi = gt_inds + (size_t)im * NN;
    const u32* ge = edges + (size_t)im * MAXE;

    if (tid == 0) { s_pos = 0; s_qcnt = 0; s_pcnt = 0; s_tpush = 0.f; s_tpull = 0.f; s_minkey = ~0ull; }
    if (tid < GG) {
        firstk[tid] = 0ull;
        const float* gt = gt_boxes + (size_t)im * GG * 4;
        gtb[tid] = make_float4(gt[tid * 4 + 0], gt[tid * 4 + 1], gt[tid * 4 + 2], gt[tid * 4 + 3]);
    }
    int lpos = 0;
    for (int j = tid; j < NN; j += STH) {
        int g = gbi[j];
        st[j] = (g >= 0) ? 0 : 2;
        lpos += (g >= 0) ? 1 : 0;
        scoreL[j] = __float_as_uint(pb[j * 5 + 4]);
        cw[j] = 0; sumA[j] = 0.f; hk[j] = 0;
    }
    lpos = wredi(lpos);
    if (lane == 0 && lpos) atomicAdd(&s_pos, lpos);
    __syncthreads();

    // ---- build LDS CSR from the edge list ----
    const int E = min(ecnt[im], MAXE);
    for (int e = tid; e < E; e += STH) atomicAdd(&cw[ge[e] >> 16], 1);
    __syncthreads();
    {   // block-wide exclusive prefix sum over 2048 counts (4 per thread)
        int j0 = tid * 4;
        int c0 = cw[j0], c1 = cw[j0 + 1], c2 = cw[j0 + 2], c3 = cw[j0 + 3];
        int s = c0 + c1 + c2 + c3;
        int incl = s;
        for (int o = 1; o < 64; o <<= 1) {
            int v = __shfl_up(incl, o);
            if (lane >= o) incl += v;
        }
        if (lane == 63) wtot[wid] = incl;
        __syncthreads();
        int wpre = 0;
        for (int wq = 0; wq < wid; ++wq) wpre += wtot[wq];
        int excl = wpre + incl - s;
        eoff[j0] = (u16)excl;
        eoff[j0 + 1] = (u16)(excl + c0);
        eoff[j0 + 2] = (u16)(excl + c0 + c1);
        eoff[j0 + 3] = (u16)(excl + c0 + c1 + c2);
        if (tid == STH - 1) eoff[NN] = (u16)(excl + s);
        cw[j0] = excl;                      // cursor = start offset (thread owns its 4 slots)
        cw[j0 + 1] = excl + c0;
        cw[j0 + 2] = excl + c0 + c1;
        cw[j0 + 3] = excl + c0 + c1 + c2;
    }
    __syncthreads();
    for (int e = tid; e < E; e += STH) {
        u32 x = ge[e];
        int pos = atomicAdd(&cw[x >> 16], 1);
        ent[pos] = (u16)(x & 0xffffu);
    }
    __syncthreads();

    // ---- fixpoint: kept <=> no kept earlier overlapper (all LDS) ----
    while (true) {
        if (tid == 0) s_unres = 0;
        __syncthreads();
        int lu = 0;
        for (int j = tid; j < NN; j += STH) {
            if (st[j] != 0) continue;
            int e0 = eoff[j], e1 = eoff[j + 1];
            bool anyK = false, anyU = false;
            for (int e = e0; e < e1; ++e) {
                unsigned char s = st[ent[e]];
                anyK |= (s == 1);
                anyU |= (s == 0);
            }
            if (anyK) st[j] = 2;
            else if (!anyU) st[j] = 1;
            else ++lu;
        }
        lu = wredi(lu);
        if (lane == 0 && lu) atomicAdd(&s_unres, lu);
        __syncthreads();
        if (s_unres == 0) break;
        __syncthreads();                  // protect s_unres reset next round
    }

    // ---- re-zero cw for use as cntA ----
    for (int j = tid; j < NN; j += STH) cw[j] = 0;
    __syncthreads();

    // ---- pass 1: kept bookkeeping + killer attribution ----
    for (int j = tid; j < NN; j += STH) {
        int g = gbi[j];
        if (st[j] == 1) {
            u64 kj = make_key(scoreL[j], j);
            atomicMin(&s_minkey, kj);
            atomicMax(&firstk[g], kj);
        } else if (g >= 0) {
            int e0 = eoff[j], e1 = eoff[j + 1];
            int ki = -1; u32 ks = 0;
            for (int e = e0; e < e1; ++e) {
                int ii = ent[e];
                if (st[ii] == 1 && (ki < 0 || earlier(scoreL[ii], ii, ks, ki))) { ki = ii; ks = scoreL[ii]; }
            }
            if (ki < 0) continue;         // cannot happen for a killed positive
            hk[ki] = 1;                   // benign race: all write 1
            float v = iou4(load_box(pb, ki), load_box(pb, j));
            int gi = gbi[ki];
            if (g != gi && v > iou4(gtb[gi], gtb[g])) {
                atomicAdd(&cw[ki], 1);
                atomicAdd(&sumA[ki], -logf(1.5f - v) * pb[j * 5 + 4]);
            }
        }
    }
    __syncthreads();

    // ---- pass 2: accumulation over kept selections (order-free) ----
    float ltpush = 0.f, ltpull = 0.f;
    int lqcnt = 0, lpcnt = 0;
    const u64 minkey = s_minkey;
    for (int i = tid; i < NN; i += STH) {
        if (st[i] != 1) continue;
        int g = gbi[i];
        u64 ky = make_key(scoreL[i], i);
        u64 fk = firstk[g];
        bool add = (ky != minkey) || (hk[i] != 0);   // any(alive_p) at this selection
        int c = cw[i];
        bool hr = fk > ky;                            // earlier kept with same gt
        if (add && c > 0) ltpush += sumA[i] / (float)c;
        if (add) lqcnt += c;
        if (hr) ++lpcnt;                              // counted even when !add (matches ref)
        if (add && hr) {
            int r = (NN - 1) - (int)(fk & 0xffffffffu);
            float v = iou4(load_box(pb, i), load_box(pb, r));
            ltpull += -logf(fmaxf(v, 1e-6f)) * pb[i * 5 + 4];
        }
    }
    ltpush = wredf(ltpush); ltpull = wredf(ltpull);
    lqcnt = wredi(lqcnt); lpcnt = wredi(lpcnt);
    if (lane == 0) {
        if (ltpush != 0.f) atomicAdd(&s_tpush, ltpush);
        if (ltpull != 0.f) atomicAdd(&s_tpull, ltpull);
        if (lqcnt) atomicAdd(&s_qcnt, lqcnt);
        if (lpcnt) atomicAdd(&s_pcnt, lpcnt);
    }
    __syncthreads();

    // ---- cross-image finalize: last-finishing block writes the B-mean ----
    if (tid == 0) {
        float valid = (s_pos > 1) ? 1.0f : 0.0f;
        float push_b = s_tpush / ((float)s_qcnt + 1e-6f) * valid;
        float pull_b = s_tpull / ((float)s_pcnt + 1e-6f) * valid;
        atomicAdd(&acc[0], push_b);
        atomicAdd(&acc[1], pull_b);
        __threadfence();
        u32 old = atomicAdd(ctr2, 1u);
        if (old == (u32)(B - 1)) {
            float ps = atomicAdd(&acc[0], 0.0f);   // coherent device-scope read
            float pl = atomicAdd(&acc[1], 0.0f);
            float inv = 1.0f / (float)B;
            out[0] = ps * inv * 1.0f;  // push_loss * PUSH_W
            out[1] = pl * inv * 1.0f;  // pull_loss * PULL_W
        }
    }
}

extern "C" void kernel_launch(void* const* d_in, const int* in_sizes, int n_in,
                              void* d_out, int out_size, void* d_ws, size_t ws_size,
                              hipStream_t stream) {
    // inputs: 0=gt_inds(B*N i32), 1=anchor_gt_inds(B*N i32),
    //         2=gt_bboxes(B*G*4 f32), 3=proposal_list(B*N*5 f32)
    const int B = in_sizes[0] / NN;
    const int* anchor_gt = (const int*)d_in[1];
    const float* gtb = (const float*)d_in[2];
    const float* props = (const float*)d_in[3];

    // ---- workspace: [ecnt B | acc 2 | ctr2 | pad][edges B*MAXE u32] ----
    char* w = (char*)d_ws;
    int* ecnt = (int*)w;
    float* acc = (float*)(w + (size_t)B * 4);
    u32* ctr2 = (u32*)(w + (size_t)B * 4 + 8);
    size_t hdr = ((size_t)B * 4 + 12 + 15) & ~(size_t)15;
    u32* edges = (u32*)(w + hdr);

    hipMemsetAsync(d_ws, 0, hdr, stream);
    pair_kernel<<<dim3(B * NPAIR), dim3(256), 0, stream>>>(anchor_gt, props, ecnt, edges);
    scan_kernel<<<dim3(B), dim3(STH), 0, stream>>>(anchor_gt, gtb, props, ecnt, edges,
                                                   acc, ctr2, (float*)d_out, B);
}

// Round 10
// 66.488 us; speedup vs baseline: 2.0929x; 2.0929x over previous
//
#include <hip/hip_runtime.h>

#define NN 2048
#define GG 64
#define TS 128
#define NT (NN / TS)                 // 16 tiles
#define NPAIR (NT * (NT + 1) / 2)    // 136 tile pairs
#define MAXE 14336                   // per-image edge cap (est. E ~ 3000)
#define EBUF 3072                    // per-block LDS edge buffer
#define STH 512                      // scan threads

typedef unsigned long long u64;
typedef unsigned short u16;
typedef unsigned int u32;

__device__ __forceinline__ float iou4(float4 a, float4 b) {
    float w = fminf(a.z, b.z) - fmaxf(a.x, b.x) + 1.0f;
    float h = fminf(a.w, b.w) - fmaxf(a.y, b.y) + 1.0f;
    w = fmaxf(w, 0.0f);
    h = fmaxf(h, 0.0f);
    float ov = w * h;
    float aa = (a.z - a.x + 1.0f) * (a.w - a.y + 1.0f);
    float ab = (b.z - b.x + 1.0f) * (b.w - b.y + 1.0f);
    return ov / (aa + ab - ov);
}

__device__ __forceinline__ float wredf(float v) {
    for (int o = 32; o > 0; o >>= 1) v += __shfl_down(v, o);
    return v;
}
__device__ __forceinline__ int wredi(int v) {
    for (int o = 32; o > 0; o >>= 1) v += __shfl_down(v, o);
    return v;
}

// selection order: earlier = higher score, tie -> lower original index.
// scores >= 0 so float bits compare as uint.
__device__ __forceinline__ bool earlier(u32 sa, int a, u32 sb, int b) {
    return (sa > sb) || (sa == sb && a < b);
}
__device__ __forceinline__ u64 make_key(u32 sbits, int j) {
    return ((u64)sbits << 32) | (u64)(NN - 1 - j);
}
__device__ __forceinline__ float4 load_box(const float* pb, int j) {
    return make_float4(pb[j * 5 + 0], pb[j * 5 + 1], pb[j * 5 + 2], pb[j * 5 + 3]);
}

// ---------------- K1: balanced LDS-tiled pair phase -> compact edge list ----------------
// grid: B*NPAIR blocks, 256 threads; block = (im, tile-pair a<=b) over original order.
// Edge append: LDS buffer + ONE ranged global atomic per block (counters 128B apart).
__global__ __launch_bounds__(256) void pair_kernel(const int* __restrict__ gt_inds,
                                                   const float* __restrict__ props,
                                                   int* __restrict__ ecnt, u32* __restrict__ edges) {
    const int im = blockIdx.x / NPAIR;
    int q = blockIdx.x % NPAIR;
    int ta = 0;
    while (q >= NT - ta) { q -= NT - ta; ++ta; }
    const int tb = ta + q;
    const float* pb = props + (size_t)im * NN * 5;
    const int* gbi = gt_inds + (size_t)im * NN;

    __shared__ float4 Abox[TS], Bbox[TS];
    __shared__ u32 Asc[TS], Bsc[TS];
    __shared__ int Ag[TS], Bg[TS];
    __shared__ u32 ebuf[EBUF];
    __shared__ int lcnt, gbase;
    const int tid = threadIdx.x;
    if (tid == 0) lcnt = 0;

    for (int t = tid; t < 2 * TS; t += 256) {
        int half = t >> 7, r = t & (TS - 1);
        int j = (half ? tb : ta) * TS + r;
        float4 bx = load_box(pb, j);
        u32 sb = __float_as_uint(pb[j * 5 + 4]);
        int g = gbi[j];
        if (half == 0) { Abox[r] = bx; Asc[r] = sb; Ag[r] = g; }
        else           { Bbox[r] = bx; Bsc[r] = sb; Bg[r] = g; }
    }
    __syncthreads();

    const int pr = tid & (TS - 1);      // row in tile A
    const int half = tid >> 7;          // column half in tile B
    const float4 rb = Abox[pr];
    const u32 rs = Asc[pr];
    const int i = ta * TS + pr;
    int* ec = ecnt + im * 32;           // 128B-padded per-image counter
    u32* ge = edges + (size_t)im * MAXE;
    if (Ag[pr] >= 0) {
        #pragma unroll 4
        for (int k = 0; k < TS / 2; ++k) {
            int jl = half * (TS / 2) + k;
            if (ta == tb && jl <= pr) continue;   // each unordered pair once
            if (Bg[jl] < 0) continue;
            float v = iou4(rb, Bbox[jl]);
            if (v > 0.5f) {
                int j = tb * TS + jl;
                int late, early;
                if (earlier(rs, i, Bsc[jl], j)) { late = j; early = i; }
                else                            { late = i; early = j; }
                u32 packed = ((u32)late << 16) | (u32)early;
                int slot = atomicAdd(&lcnt, 1);            // LDS atomic: fast
                if (slot < EBUF) ebuf[slot] = packed;
                else {                                      // spill (essentially never)
                    int gs = atomicAdd(ec, 1);
                    if (gs < MAXE) ge[gs] = packed;
                }
            }
        }
    }
    __syncthreads();
    const int n = min(lcnt, EBUF);
    if (tid == 0) gbase = (n > 0) ? atomicAdd(ec, n) : 0;   // one global atomic per block
    __syncthreads();
    for (int e = tid; e < n; e += 256) {
        int gidx = gbase + e;
        if (gidx < MAXE) ge[gidx] = ebuf[e];                // coalesced copy
    }
}

// ---------------- K2: LDS CSR build + fixpoint + attribution + fused finalize ----------------
__global__ __launch_bounds__(STH) void scan_kernel(const int* __restrict__ gt_inds,
                                                   const float* __restrict__ gt_boxes,
                                                   const float* __restrict__ props,
                                                   const int* __restrict__ ecnt, const u32* __restrict__ edges,
                                                   float* __restrict__ acc, u32* __restrict__ ctr2,
                                                   float* __restrict__ out, int B) {
    __shared__ u32 scoreL[NN];            // 8 KB (float bits)
    __shared__ float sumA[NN];            // 8 KB
    __shared__ int cw[NN];                // 8 KB: count -> cursor -> cntA (re-zeroed)
    __shared__ u16 eoff[NN + 1];          // 4 KB
    __shared__ u16 ent[MAXE];             // 28 KB
    __shared__ unsigned char st[NN];      // 0=unresolved 1=kept 2=killed
    __shared__ unsigned char hk[NN];
    __shared__ float4 gtb[GG];            // 1 KB
    __shared__ u64 firstk[GG];            // max key among kept per gt (0 = none)
    __shared__ int wtot[STH / 64];
    __shared__ u64 s_minkey;
    __shared__ int s_unres, s_pos, s_qcnt, s_pcnt;
    __shared__ float s_tpush, s_tpull;

    const int im = blockIdx.x, tid = threadIdx.x;
    const int lane = tid & 63, wid = tid >> 6;
    const float* pb = props + (size_t)im * NN * 5;
    const int* gbi = gt_inds + (size_t)im * NN;
    const u32* ge = edges + (size_t)im * MAXE;

    if (tid == 0) { s_pos = 0; s_qcnt = 0; s_pcnt = 0; s_tpush = 0.f; s_tpull = 0.f; s_minkey = ~0ull; }
    if (tid < GG) {
        firstk[tid] = 0ull;
        const float* gt = gt_boxes + (size_t)im * GG * 4;
        gtb[tid] = make_float4(gt[tid * 4 + 0], gt[tid * 4 + 1], gt[tid * 4 + 2], gt[tid * 4 + 3]);
    }
    int lpos = 0;
    for (int j = tid; j < NN; j += STH) {
        int g = gbi[j];
        st[j] = (g >= 0) ? 0 : 2;
        lpos += (g >= 0) ? 1 : 0;
        scoreL[j] = __float_as_uint(pb[j * 5 + 4]);
        cw[j] = 0; sumA[j] = 0.f; hk[j] = 0;
    }
    lpos = wredi(lpos);
    if (lane == 0 && lpos) atomicAdd(&s_pos, lpos);
    __syncthreads();

    // ---- build LDS CSR from the edge list ----
    const int E = min(ecnt[im * 32], MAXE);
    for (int e = tid; e < E; e += STH) atomicAdd(&cw[ge[e] >> 16], 1);
    __syncthreads();
    {   // block-wide exclusive prefix sum over 2048 counts (4 per thread)
        int j0 = tid * 4;
        int c0 = cw[j0], c1 = cw[j0 + 1], c2 = cw[j0 + 2], c3 = cw[j0 + 3];
        int s = c0 + c1 + c2 + c3;
        int incl = s;
        for (int o = 1; o < 64; o <<= 1) {
            int v = __shfl_up(incl, o);
            if (lane >= o) incl += v;
        }
        if (lane == 63) wtot[wid] = incl;
        __syncthreads();
        int wpre = 0;
        for (int wq = 0; wq < wid; ++wq) wpre += wtot[wq];
        int excl = wpre + incl - s;
        eoff[j0] = (u16)excl;
        eoff[j0 + 1] = (u16)(excl + c0);
        eoff[j0 + 2] = (u16)(excl + c0 + c1);
        eoff[j0 + 3] = (u16)(excl + c0 + c1 + c2);
        if (tid == STH - 1) eoff[NN] = (u16)(excl + s);
        cw[j0] = excl;                      // cursor = start offset
        cw[j0 + 1] = excl + c0;
        cw[j0 + 2] = excl + c0 + c1;
        cw[j0 + 3] = excl + c0 + c1 + c2;
    }
    __syncthreads();
    for (int e = tid; e < E; e += STH) {
        u32 x = ge[e];
        int pos = atomicAdd(&cw[x >> 16], 1);
        ent[pos] = (u16)(x & 0xffffu);
    }
    __syncthreads();

    // ---- fixpoint: kept <=> no kept earlier overlapper (all LDS) ----
    while (true) {
        if (tid == 0) s_unres = 0;
        __syncthreads();
        int lu = 0;
        for (int j = tid; j < NN; j += STH) {
            if (st[j] != 0) continue;
            int e0 = eoff[j], e1 = eoff[j + 1];
            bool anyK = false, anyU = false;
            for (int e = e0; e < e1; ++e) {
                unsigned char s = st[ent[e]];
                anyK |= (s == 1);
                anyU |= (s == 0);
            }
            if (anyK) st[j] = 2;
            else if (!anyU) st[j] = 1;
            else ++lu;
        }
        lu = wredi(lu);
        if (lane == 0 && lu) atomicAdd(&s_unres, lu);
        __syncthreads();
        if (s_unres == 0) break;
        __syncthreads();                  // protect s_unres reset next round
    }

    // ---- re-zero cw for use as cntA ----
    for (int j = tid; j < NN; j += STH) cw[j] = 0;
    __syncthreads();

    // ---- pass 1: kept bookkeeping + killer attribution ----
    for (int j = tid; j < NN; j += STH) {
        int g = gbi[j];
        if (st[j] == 1) {
            u64 kj = make_key(scoreL[j], j);
            atomicMin(&s_minkey, kj);
            atomicMax(&firstk[g], kj);
        } else if (g >= 0) {
            int e0 = eoff[j], e1 = eoff[j + 1];
            int ki = -1; u32 ks = 0;
            for (int e = e0; e < e1; ++e) {
                int ii = ent[e];
                if (st[ii] == 1 && (ki < 0 || earlier(scoreL[ii], ii, ks, ki))) { ki = ii; ks = scoreL[ii]; }
            }
            if (ki < 0) continue;         // cannot happen for a killed positive
            hk[ki] = 1;                   // benign race: all write 1
            float v = iou4(load_box(pb, ki), load_box(pb, j));
            int gi = gbi[ki];
            if (g != gi && v > iou4(gtb[gi], gtb[g])) {
                atomicAdd(&cw[ki], 1);
                atomicAdd(&sumA[ki], -logf(1.5f - v) * pb[j * 5 + 4]);
            }
        }
    }
    __syncthreads();

    // ---- pass 2: accumulation over kept selections (order-free) ----
    float ltpush = 0.f, ltpull = 0.f;
    int lqcnt = 0, lpcnt = 0;
    const u64 minkey = s_minkey;
    for (int i = tid; i < NN; i += STH) {
        if (st[i] != 1) continue;
        int g = gbi[i];
        u64 ky = make_key(scoreL[i], i);
        u64 fk = firstk[g];
        bool add = (ky != minkey) || (hk[i] != 0);   // any(alive_p) at this selection
        int c = cw[i];
        bool hr = fk > ky;                            // earlier kept with same gt
        if (add && c > 0) ltpush += sumA[i] / (float)c;
        if (add) lqcnt += c;
        if (hr) ++lpcnt;                              // counted even when !add (matches ref)
        if (add && hr) {
            int r = (NN - 1) - (int)(fk & 0xffffffffu);
            float v = iou4(load_box(pb, i), load_box(pb, r));
            ltpull += -logf(fmaxf(v, 1e-6f)) * pb[i * 5 + 4];
        }
    }
    ltpush = wredf(ltpush); ltpull = wredf(ltpull);
    lqcnt = wredi(lqcnt); lpcnt = wredi(lpcnt);
    if (lane == 0) {
        if (ltpush != 0.f) atomicAdd(&s_tpush, ltpush);
        if (ltpull != 0.f) atomicAdd(&s_tpull, ltpull);
        if (lqcnt) atomicAdd(&s_qcnt, lqcnt);
        if (lpcnt) atomicAdd(&s_pcnt, lpcnt);
    }
    __syncthreads();

    // ---- cross-image finalize: last-finishing block writes the B-mean ----
    if (tid == 0) {
        float valid = (s_pos > 1) ? 1.0f : 0.0f;
        float push_b = s_tpush / ((float)s_qcnt + 1e-6f) * valid;
        float pull_b = s_tpull / ((float)s_pcnt + 1e-6f) * valid;
        atomicAdd(&acc[0], push_b);
        atomicAdd(&acc[1], pull_b);
        __threadfence();
        u32 old = atomicAdd(ctr2, 1u);
        if (old == (u32)(B - 1)) {
            float ps = atomicAdd(&acc[0], 0.0f);   // coherent device-scope read
            float pl = atomicAdd(&acc[1], 0.0f);
            float inv = 1.0f / (float)B;
            out[0] = ps * inv * 1.0f;  // push_loss * PUSH_W
            out[1] = pl * inv * 1.0f;  // pull_loss * PULL_W
        }
    }
}

extern "C" void kernel_launch(void* const* d_in, const int* in_sizes, int n_in,
                              void* d_out, int out_size, void* d_ws, size_t ws_size,
                              hipStream_t stream) {
    // inputs: 0=gt_inds(B*N i32), 1=anchor_gt_inds(B*N i32),
    //         2=gt_bboxes(B*G*4 f32), 3=proposal_list(B*N*5 f32)
    const int B = in_sizes[0] / NN;
    const int* anchor_gt = (const int*)d_in[1];
    const float* gtb = (const float*)d_in[2];
    const float* props = (const float*)d_in[3];

    // ---- workspace: [ecnt B*128B | acc 2f | ctr2 | pad][edges B*MAXE u32] ----
    char* w = (char*)d_ws;
    int* ecnt = (int*)w;                                  // im * 32 ints (128B apart)
    float* acc = (float*)(w + (size_t)B * 128);
    u32* ctr2 = (u32*)(w + (size_t)B * 128 + 8);
    size_t hdr = ((size_t)B * 128 + 12 + 127) & ~(size_t)127;
    u32* edges = (u32*)(w + hdr);

    hipMemsetAsync(d_ws, 0, hdr, stream);
    pair_kernel<<<dim3(B * NPAIR), dim3(256), 0, stream>>>(anchor_gt, props, ecnt, edges);
    scan_kernel<<<dim3(B), dim3(STH), 0, stream>>>(anchor_gt, gtb, props, ecnt, edges,
                                                   acc, ctr2, (float*)d_out, B);
}

// Round 11
// 61.020 us; speedup vs baseline: 2.2805x; 1.0896x over previous
//
#include <hip/hip_runtime.h>

#define NN 2048
#define GG 64
#define TS 128
#define NT (NN / TS)                 // 16 tiles
#define NPAIR (NT * (NT + 1) / 2)    // 136 tile pairs
#define MAXE 14336                   // per-image edge cap (est. E ~ 3000)
#define EBUF 3072                    // per-block LDS edge buffer
#define STH 512                      // scan threads

typedef unsigned long long u64;
typedef unsigned short u16;
typedef unsigned int u32;

__device__ __forceinline__ float iou4(float4 a, float4 b) {
    float w = fminf(a.z, b.z) - fmaxf(a.x, b.x) + 1.0f;
    float h = fminf(a.w, b.w) - fmaxf(a.y, b.y) + 1.0f;
    w = fmaxf(w, 0.0f);
    h = fmaxf(h, 0.0f);
    float ov = w * h;
    float aa = (a.z - a.x + 1.0f) * (a.w - a.y + 1.0f);
    float ab = (b.z - b.x + 1.0f) * (b.w - b.y + 1.0f);
    return ov / (aa + ab - ov);
}

__device__ __forceinline__ float wredf(float v) {
    for (int o = 32; o > 0; o >>= 1) v += __shfl_down(v, o);
    return v;
}
__device__ __forceinline__ int wredi(int v) {
    for (int o = 32; o > 0; o >>= 1) v += __shfl_down(v, o);
    return v;
}

// selection order: earlier = higher score, tie -> lower original index.
// scores >= 0 so float bits compare as uint.
__device__ __forceinline__ bool earlier(u32 sa, int a, u32 sb, int b) {
    return (sa > sb) || (sa == sb && a < b);
}
__device__ __forceinline__ u64 make_key(u32 sbits, int j) {
    return ((u64)sbits << 32) | (u64)(NN - 1 - j);
}
__device__ __forceinline__ float4 load_box(const float* pb, int j) {
    return make_float4(pb[j * 5 + 0], pb[j * 5 + 1], pb[j * 5 + 2], pb[j * 5 + 3]);
}

// ---------------- K1: balanced LDS-tiled pair phase -> compact edge list ----------------
__global__ __launch_bounds__(256) void pair_kernel(const int* __restrict__ gt_inds,
                                                   const float* __restrict__ props,
                                                   int* __restrict__ ecnt, u32* __restrict__ edges) {
    const int im = blockIdx.x / NPAIR;
    int q = blockIdx.x % NPAIR;
    int ta = 0;
    while (q >= NT - ta) { q -= NT - ta; ++ta; }
    const int tb = ta + q;
    const float* pb = props + (size_t)im * NN * 5;
    const int* gbi = gt_inds + (size_t)im * NN;

    __shared__ float4 Abox[TS], Bbox[TS];
    __shared__ u32 Asc[TS], Bsc[TS];
    __shared__ int Ag[TS], Bg[TS];
    __shared__ u32 ebuf[EBUF];
    __shared__ int lcnt, gbase;
    const int tid = threadIdx.x;
    if (tid == 0) lcnt = 0;

    for (int t = tid; t < 2 * TS; t += 256) {
        int half = t >> 7, r = t & (TS - 1);
        int j = (half ? tb : ta) * TS + r;
        float4 bx = load_box(pb, j);
        u32 sb = __float_as_uint(pb[j * 5 + 4]);
        int g = gbi[j];
        if (half == 0) { Abox[r] = bx; Asc[r] = sb; Ag[r] = g; }
        else           { Bbox[r] = bx; Bsc[r] = sb; Bg[r] = g; }
    }
    __syncthreads();

    const int pr = tid & (TS - 1);      // row in tile A
    const int half = tid >> 7;          // column half in tile B
    const float4 rb = Abox[pr];
    const u32 rs = Asc[pr];
    const int i = ta * TS + pr;
    int* ec = ecnt + im * 32;           // 128B-padded per-image counter
    u32* ge = edges + (size_t)im * MAXE;
    if (Ag[pr] >= 0) {
        #pragma unroll 4
        for (int k = 0; k < TS / 2; ++k) {
            int jl = half * (TS / 2) + k;
            if (ta == tb && jl <= pr) continue;   // each unordered pair once
            if (Bg[jl] < 0) continue;
            float v = iou4(rb, Bbox[jl]);
            if (v > 0.5f) {
                int j = tb * TS + jl;
                int late, early;
                if (earlier(rs, i, Bsc[jl], j)) { late = j; early = i; }
                else                            { late = i; early = j; }
                u32 packed = ((u32)late << 16) | (u32)early;
                int slot = atomicAdd(&lcnt, 1);            // LDS atomic: fast
                if (slot < EBUF) ebuf[slot] = packed;
                else {                                      // spill (essentially never)
                    int gs = atomicAdd(ec, 1);
                    if (gs < MAXE) ge[gs] = packed;
                }
            }
        }
    }
    __syncthreads();
    const int n = min(lcnt, EBUF);
    if (tid == 0) gbase = (n > 0) ? atomicAdd(ec, n) : 0;   // one global atomic per block
    __syncthreads();
    for (int e = tid; e < n; e += 256) {
        int gidx = gbase + e;
        if (gidx < MAXE) ge[gidx] = ebuf[e];                // coalesced copy
    }
}

// ---------------- K2: LDS CSR + worklist fixpoint + attribution + fused finalize ----------------
union SumWl {
    float sumA[NN];                   // 8 KB (pass 1/2 only)
    u16 wl[2][NN];                    // fixpoint worklists
};

__global__ __launch_bounds__(STH) void scan_kernel(const int* __restrict__ gt_inds,
                                                   const float* __restrict__ gt_boxes,
                                                   const float* __restrict__ props,
                                                   const int* __restrict__ ecnt, const u32* __restrict__ edges,
                                                   float* __restrict__ acc, u32* __restrict__ ctr2,
                                                   float* __restrict__ out, int B) {
    __shared__ u32 scoreL[NN];            // 8 KB (float bits)
    __shared__ SumWl u;                   // 8 KB
    __shared__ int cw[NN];                // 8 KB: count -> cursor -> cntA
    __shared__ u16 eoff[NN + 1];          // 4 KB
    __shared__ u16 ent[MAXE];             // 28 KB
    __shared__ unsigned char st[NN];      // 0=unresolved 1=kept 2=killed
    __shared__ unsigned char hk[NN];
    __shared__ float4 gtb[GG];            // 1 KB
    __shared__ u64 firstk[GG];            // max key among kept per gt (0 = none)
    __shared__ int wtot[STH / 64];
    __shared__ int s_cnt[2];              // parity worklist counters
    __shared__ u64 s_minkey;
    __shared__ int s_pos, s_qcnt, s_pcnt;
    __shared__ float s_tpush, s_tpull;

    const int im = blockIdx.x, tid = threadIdx.x;
    const int lane = tid & 63, wid = tid >> 6;
    const float* pb = props + (size_t)im * NN * 5;
    const int* gbi = gt_inds + (size_t)im * NN;
    const u32* ge = edges + (size_t)im * MAXE;
    volatile unsigned char* vst = st;     // fixpoint reads must not be register-cached

    if (tid == 0) {
        s_pos = 0; s_qcnt = 0; s_pcnt = 0; s_tpush = 0.f; s_tpull = 0.f; s_minkey = ~0ull;
        s_cnt[0] = 0; s_cnt[1] = 0;
    }
    if (tid < GG) {
        firstk[tid] = 0ull;
        const float* gt = gt_boxes + (size_t)im * GG * 4;
        gtb[tid] = make_float4(gt[tid * 4 + 0], gt[tid * 4 + 1], gt[tid * 4 + 2], gt[tid * 4 + 3]);
    }
    int lpos = 0;
    for (int j = tid; j < NN; j += STH) {
        int g = gbi[j];
        st[j] = (g >= 0) ? 0 : 2;
        lpos += (g >= 0) ? 1 : 0;
        scoreL[j] = __float_as_uint(pb[j * 5 + 4]);
        cw[j] = 0; hk[j] = 0;
    }
    lpos = wredi(lpos);
    if (lane == 0 && lpos) atomicAdd(&s_pos, lpos);
    __syncthreads();

    // ---- build LDS CSR from the edge list ----
    const int E = min(ecnt[im * 32], MAXE);
    for (int e = tid; e < E; e += STH) atomicAdd(&cw[ge[e] >> 16], 1);
    __syncthreads();
    {   // block-wide exclusive prefix sum over 2048 counts (4 per thread)
        int j0 = tid * 4;
        int c0 = cw[j0], c1 = cw[j0 + 1], c2 = cw[j0 + 2], c3 = cw[j0 + 3];
        int s = c0 + c1 + c2 + c3;
        int incl = s;
        for (int o = 1; o < 64; o <<= 1) {
            int v = __shfl_up(incl, o);
            if (lane >= o) incl += v;
        }
        if (lane == 63) wtot[wid] = incl;
        __syncthreads();
        int wpre = 0;
        for (int wq = 0; wq < wid; ++wq) wpre += wtot[wq];
        int excl = wpre + incl - s;
        eoff[j0] = (u16)excl;
        eoff[j0 + 1] = (u16)(excl + c0);
        eoff[j0 + 2] = (u16)(excl + c0 + c1);
        eoff[j0 + 3] = (u16)(excl + c0 + c1 + c2);
        if (tid == STH - 1) eoff[NN] = (u16)(excl + s);
        cw[j0] = excl;
        cw[j0 + 1] = excl + c0;
        cw[j0 + 2] = excl + c0 + c1;
        cw[j0 + 3] = excl + c0 + c1 + c2;
    }
    __syncthreads();
    for (int e = tid; e < E; e += STH) {
        u32 x = ge[e];
        int pos = atomicAdd(&cw[x >> 16], 1);
        ent[pos] = (u16)(x & 0xffffu);
    }
    __syncthreads();

    // ---- fixpoint round 1: full sweep, compact unresolved into worklist 0 ----
    for (int j = tid; j < NN; j += STH) {
        if (st[j] != 0) continue;
        int e0 = eoff[j], e1 = eoff[j + 1];
        bool anyK = false, anyU = false;
        for (int e = e0; e < e1; ++e) {
            unsigned char s = vst[ent[e]];
            anyK |= (s == 1);
            anyU |= (s == 0);
        }
        if (anyK) st[j] = 2;
        else if (!anyU) st[j] = 1;
        else { int pos = atomicAdd(&s_cnt[0], 1); u.wl[0][pos] = (u16)j; }
    }
    __syncthreads();

    // ---- fixpoint rounds: worklist only, 3 relaxation sub-sweeps per barrier ----
    int src = 0;
    int nwl = s_cnt[0];
    while (nwl > 0) {
        #pragma unroll
        for (int r = 0; r < 2; ++r) {       // benign-race relaxations (monotone st)
            for (int w = tid; w < nwl; w += STH) {
                int j = u.wl[src][w];
                if (st[j] != 0) continue;
                int e0 = eoff[j], e1 = eoff[j + 1];
                bool anyK = false, anyU = false;
                for (int e = e0; e < e1; ++e) {
                    unsigned char s = vst[ent[e]];
                    anyK |= (s == 1);
                    anyU |= (s == 0);
                }
                if (anyK) st[j] = 2;
                else if (!anyU) st[j] = 1;
            }
        }
        // 3rd sweep: resolve-or-append to the other worklist
        for (int w = tid; w < nwl; w += STH) {
            int j = u.wl[src][w];
            if (st[j] != 0) continue;
            int e0 = eoff[j], e1 = eoff[j + 1];
            bool anyK = false, anyU = false;
            for (int e = e0; e < e1; ++e) {
                unsigned char s = vst[ent[e]];
                anyK |= (s == 1);
                anyU |= (s == 0);
            }
            if (anyK) st[j] = 2;
            else if (!anyU) st[j] = 1;
            else { int pos = atomicAdd(&s_cnt[src ^ 1], 1); u.wl[src ^ 1][pos] = (u16)j; }
        }
        __syncthreads();                    // appends complete; counts final
        nwl = s_cnt[src ^ 1];
        if (tid == 0) s_cnt[src] = 0;       // reset for reuse two rounds from now
        src ^= 1;
        __syncthreads();                    // reset visible before next appends
    }

    // ---- worklists dead; zero sumA and cw (cntA) ----
    for (int j = tid; j < NN; j += STH) { u.sumA[j] = 0.f; cw[j] = 0; }
    __syncthreads();

    // ---- pass 1: kept bookkeeping + killer attribution ----
    for (int j = tid; j < NN; j += STH) {
        int g = gbi[j];
        if (st[j] == 1) {
            u64 kj = make_key(scoreL[j], j);
            atomicMin(&s_minkey, kj);
            atomicMax(&firstk[g], kj);
        } else if (g >= 0) {
            int e0 = eoff[j], e1 = eoff[j + 1];
            int ki = -1; u32 ks = 0;
            for (int e = e0; e < e1; ++e) {
                int ii = ent[e];
                if (st[ii] == 1 && (ki < 0 || earlier(scoreL[ii], ii, ks, ki))) { ki = ii; ks = scoreL[ii]; }
            }
            if (ki < 0) continue;         // cannot happen for a killed positive
            hk[ki] = 1;                   // benign race: all write 1
            float v = iou4(load_box(pb, ki), load_box(pb, j));
            int gi = gbi[ki];
            if (g != gi && v > iou4(gtb[gi], gtb[g])) {
                atomicAdd(&cw[ki], 1);
                atomicAdd(&u.sumA[ki], -logf(1.5f - v) * pb[j * 5 + 4]);
            }
        }
    }
    __syncthreads();

    // ---- pass 2: accumulation over kept selections (order-free) ----
    float ltpush = 0.f, ltpull = 0.f;
    int lqcnt = 0, lpcnt = 0;
    const u64 minkey = s_minkey;
    for (int i = tid; i < NN; i += STH) {
        if (st[i] != 1) continue;
        int g = gbi[i];
        u64 ky = make_key(scoreL[i], i);
        u64 fk = firstk[g];
        bool add = (ky != minkey) || (hk[i] != 0);   // any(alive_p) at this selection
        int c = cw[i];
        bool hr = fk > ky;                            // earlier kept with same gt
        if (add && c > 0) ltpush += u.sumA[i] / (float)c;
        if (add) lqcnt += c;
        if (hr) ++lpcnt;                              // counted even when !add (matches ref)
        if (add && hr) {
            int r = (NN - 1) - (int)(fk & 0xffffffffu);
            float v = iou4(load_box(pb, i), load_box(pb, r));
            ltpull += -logf(fmaxf(v, 1e-6f)) * pb[i * 5 + 4];
        }
    }
    ltpush = wredf(ltpush); ltpull = wredf(ltpull);
    lqcnt = wredi(lqcnt); lpcnt = wredi(lpcnt);
    if (lane == 0) {
        if (ltpush != 0.f) atomicAdd(&s_tpush, ltpush);
        if (ltpull != 0.f) atomicAdd(&s_tpull, ltpull);
        if (lqcnt) atomicAdd(&s_qcnt, lqcnt);
        if (lpcnt) atomicAdd(&s_pcnt, lpcnt);
    }
    __syncthreads();

    // ---- cross-image finalize: last-finishing block writes the B-mean ----
    if (tid == 0) {
        float valid = (s_pos > 1) ? 1.0f : 0.0f;
        float push_b = s_tpush / ((float)s_qcnt + 1e-6f) * valid;
        float pull_b = s_tpull / ((float)s_pcnt + 1e-6f) * valid;
        atomicAdd(&acc[0], push_b);
        atomicAdd(&acc[1], pull_b);
        __threadfence();
        u32 old = atomicAdd(ctr2, 1u);
        if (old == (u32)(B - 1)) {
            float ps = atomicAdd(&acc[0], 0.0f);   // coherent device-scope read
            float pl = atomicAdd(&acc[1], 0.0f);
            float inv = 1.0f / (float)B;
            out[0] = ps * inv * 1.0f;  // push_loss * PUSH_W
            out[1] = pl * inv * 1.0f;  // pull_loss * PULL_W
        }
    }
}

extern "C" void kernel_launch(void* const* d_in, const int* in_sizes, int n_in,
                              void* d_out, int out_size, void* d_ws, size_t ws_size,
                              hipStream_t stream) {
    // inputs: 0=gt_inds(B*N i32), 1=anchor_gt_inds(B*N i32),
    //         2=gt_bboxes(B*G*4 f32), 3=proposal_list(B*N*5 f32)
    const int B = in_sizes[0] / NN;
    const int* anchor_gt = (const int*)d_in[1];
    const float* gtb = (const float*)d_in[2];
    const float* props = (const float*)d_in[3];

    // ---- workspace: [ecnt B*128B | acc 2f | ctr2 | pad][edges B*MAXE u32] ----
    char* w = (char*)d_ws;
    int* ecnt = (int*)w;                                  // im * 32 ints (128B apart)
    float* acc = (float*)(w + (size_t)B * 128);
    u32* ctr2 = (u32*)(w + (size_t)B * 128 + 8);
    size_t hdr = ((size_t)B * 128 + 12 + 127) & ~(size_t)127;
    u32* edges = (u32*)(w + hdr);

    hipMemsetAsync(d_ws, 0, hdr, stream);
    pair_kernel<<<dim3(B * NPAIR), dim3(256), 0, stream>>>(anchor_gt, props, ecnt, edges);
    scan_kernel<<<dim3(B), dim3(STH), 0, stream>>>(anchor_gt, gtb, props, ecnt, edges,
                                                   acc, ctr2, (float*)d_out, B);
}